// Round 17
// baseline (112.928 us; speedup 1.0000x reference)
//
#include <hip/hip_runtime.h>

#define Nn 1024

typedef __attribute__((ext_vector_type(8))) short short8v;
typedef __attribute__((ext_vector_type(4))) float floatx4;

// hardware-rate reciprocal / sqrt (v_rcp_f32 / v_sqrt_f32, ~1ulp).
__device__ __forceinline__ float frcp(float v)  { return __builtin_amdgcn_rcpf(v); }
__device__ __forceinline__ float fsilu(float v) { return v * frcp(1.0f + __expf(-v)); }
__device__ __forceinline__ float fsig(float v)  { return frcp(1.0f + __expf(-v)); }
__device__ __forceinline__ float ftanh10(float v){ return 10.0f - 20.0f * frcp(__expf(2.0f * v) + 1.0f); }

// 2x f32 -> packed bf16 (RNE) in ONE instruction (no builtin on gfx950 — T12)
__device__ __forceinline__ unsigned cvtpk(float lo, float hi) {
    unsigned r;
    asm("v_cvt_pk_bf16_f32 %0, %1, %2" : "=v"(r) : "v"(lo), "v"(hi));
    return r;
}

union I4S8 { int4 i; short8v s; };

// Kernel A: ha = h@Wa^T + eb1 (f32) ; hbb = bf16(h@Wb^T)
__global__ __launch_bounds__(256) void precompute_kernel(
    const float* __restrict__ h, const float* __restrict__ ew1,
    const float* __restrict__ eb1, float* __restrict__ ha,
    unsigned short* __restrict__ hbb)
{
    int t = blockIdx.x * 256 + threadIdx.x;   // 0 .. 2*65536-1
    int which = t >> 16;
    int rem = t & 65535;
    int i = rem >> 6, o = rem & 63;
    const float* hrow = h + i * 64;
    const float* wrow;
    float acc;
    if (which == 0) { wrow = ew1 + o * 130;      acc = eb1[o]; }
    else            { wrow = ew1 + o * 130 + 64; acc = 0.0f;   }
    #pragma unroll
    for (int k = 0; k < 64; ++k) acc = fmaf(hrow[k], wrow[k], acc);
    if (which == 0) ha[rem]  = acc;
    else            hbb[rem] = (unsigned short)(cvtpk(acc, acc) & 0xffffu);
}

// Edge pipeline. 2048 blocks x 256 thr (4 waves): block b owns node b>>1 and
// j-half b&1; wave owns 128 j's in 8 chunks of 16. R14 body (best, 90.4us)
// with ONE change: weight fragments back in REGISTERS (R7-style, loaded once
// from global). Occupancy has been pinned at 3 waves/SIMD (~170-reg budget)
// for 5 rounds, so the ~64 extra regs are free — and this deletes 16
// ds_read_b128 + the per-chunk lidx volatile-asm fence from every chunk's
// dependency chain (the chain measured ~10k cyc vs ~840 issue cyc).
// cvec stays LDS+laundered (keeps ~96 regs of constants out of the file).
__global__ __launch_bounds__(256) __attribute__((amdgpu_waves_per_eu(3, 8)))
void edge_mfma_kernel(
    const float* __restrict__ x, const float* __restrict__ Lp,
    const float* __restrict__ ha, const unsigned short* __restrict__ hbb,
    const float* __restrict__ ew1, const float* __restrict__ ew2,
    const float* __restrict__ eb2, const float* __restrict__ chw,
    const float* __restrict__ chb, const float* __restrict__ aw,
    const float* __restrict__ ab, const float* __restrict__ cww,
    float* __restrict__ agg_parts, float* __restrict__ delta_parts)
{
    __shared__ __align__(16) float cvec[384];     // eb2|aw|chb|cww|ha_row|wr_row (64 each)
    __shared__ float redagg[4][64];
    __shared__ float sdel[4][3];

    const int tid  = threadIdx.x;
    const int wave = tid >> 6, lane = tid & 63;
    const int lr = lane & 15, g = lane >> 4;
    const int i0 = blockIdx.x >> 1;
    const int half = blockIdx.x & 1;
    const int jbase = half * 512 + wave * 128;
    const int ghi  = g >> 1;
    const int selA = (lr + ((g & 1) << 5)) << 2;   // bpermute byte addr
    const int selB = selA + 64;

    // weight fragments in registers (bf16): row n = lane&15, k 8-contig per g
    short8v bw2[2][4], bwc[2][4];
    #pragma unroll
    for (int kt = 0; kt < 2; ++kt)
      #pragma unroll
      for (int nt = 0; nt < 4; ++nt) {
        int n = nt * 16 + lr;
        int k0 = kt * 32 + g * 8;
        float4 lo = *(const float4*)(ew2 + n * 64 + k0);
        float4 hi = *(const float4*)(ew2 + n * 64 + k0 + 4);
        union { short8v s; unsigned u[4]; } pk;
        pk.u[0] = cvtpk(lo.x, lo.y); pk.u[1] = cvtpk(lo.z, lo.w);
        pk.u[2] = cvtpk(hi.x, hi.y); pk.u[3] = cvtpk(hi.z, hi.w);
        bw2[kt][nt] = pk.s;
        lo = *(const float4*)(chw + n * 64 + k0);
        hi = *(const float4*)(chw + n * 64 + k0 + 4);
        pk.u[0] = cvtpk(lo.x, lo.y); pk.u[1] = cvtpk(lo.z, lo.w);
        pk.u[2] = cvtpk(hi.x, hi.y); pk.u[3] = cvtpk(hi.z, hi.w);
        bwc[kt][nt] = pk.s;
      }

    // constant vectors -> LDS (re-read per chunk; keeps them out of registers)
    if (tid < 64) {
      cvec[tid]       = eb2[tid];
      cvec[64 + tid]  = aw[tid];
      cvec[128 + tid] = chb[tid];
      cvec[192 + tid] = cww[tid];
      cvec[256 + tid] = ha[i0 * 64 + tid];
      cvec[320 + tid] = ew1[tid * 130 + 128] + ew1[tid * 130 + 129];
    }

    const float L = Lp[0], invL = frcp(L);
    const float ab0 = ab[0];

    floatx4 agg4[4];
    #pragma unroll
    for (int nt = 0; nt < 4; ++nt) agg4[nt] = (floatx4){0.f, 0.f, 0.f, 0.f};
    float dp0 = 0.f, dp1 = 0.f, dp2 = 0.f;

    __syncthreads();

    const float xi0 = x[i0 * 3 + 0], xi1 = x[i0 * 3 + 1], xi2 = x[i0 * 3 + 2];

    // prefetch bf16 hb fragment rows for chunk 0 (this lane's edge row lr)
    int4 hpre0, hpre1;
    {
      const unsigned short* hn = hbb + (jbase + lr) * 64 + g * 8;
      hpre0 = *(const int4*)(hn);        // channels kt=0: g*8 .. +7
      hpre1 = *(const int4*)(hn + 32);   // channels kt=1: 32+g*8 .. +7
    }

    for (int jc = 0; jc < 8; ++jc) {
      // laundered offsets: keep per-chunk cvec LDS reads opaque to LICM
      unsigned cb = (unsigned)(g << 4);          // g*4 floats (bias vectors)
      asm volatile("" : "+v"(cb));
      unsigned hbo = (unsigned)(g << 5);         // g*8 floats (ha/wr rows)
      asm volatile("" : "+v"(hbo));
      const float* cvp = (const float*)((const char*)cvec + cb);
      const float* hvp = (const float*)((const char*)cvec + 1024 + hbo);

      int4 hc0 = hpre0, hc1 = hpre1;
      if (jc < 7) {   // issue next chunk's hb loads NOW; latency hides under compute
        const unsigned short* hn = hbb + (jbase + (jc + 1) * 16 + lr) * 64 + g * 8;
        hpre0 = *(const int4*)(hn);
        hpre1 = *(const int4*)(hn + 32);
      }

      // ---- geometry for own edge (i0, j): all lanes, row = lr (x is L1-hot) ----
      const int j = jbase + jc * 16 + lr;
      float xd0 = xi0 - x[j * 3 + 0];
      float xd1 = xi1 - x[j * 3 + 1];
      float xd2 = xi2 - x[j * 3 + 2];
      float d0 = xd0 - L * floorf(fmaf(xd0, invL, 0.5f));
      float d1 = xd1 - L * floorf(fmaf(xd1, invL, 0.5f));
      float d2 = xd2 - L * floorf(fmaf(xd2, invL, 0.5f));
      float radial = d0 * d0 + d1 * d1 + d2 * d2;
      float cinv = frcp(__builtin_amdgcn_sqrtf(radial + 1e-8f) + 1.0f);
      float dx0 = d0 * cinv, dx1 = d1 * cinv, dx2 = d2 * cinv;

      // ---- build T fragment in registers: silu(ha + hb + radial*wr) -> bf16 ----
      short8v tf[2];
      #pragma unroll
      for (int kt = 0; kt < 2; ++kt) {
        const int4 u = kt ? hc1 : hc0;
        unsigned uw[4] = {(unsigned)u.x, (unsigned)u.y, (unsigned)u.z, (unsigned)u.w};
        floatx4 ha0 = *(const floatx4*)(hvp + kt * 32);
        floatx4 ha1 = *(const floatx4*)(hvp + kt * 32 + 4);
        floatx4 wr0 = *(const floatx4*)(hvp + 64 + kt * 32);
        floatx4 wr1 = *(const floatx4*)(hvp + 64 + kt * 32 + 4);
        float hAv[8] = {ha0[0], ha0[1], ha0[2], ha0[3], ha1[0], ha1[1], ha1[2], ha1[3]};
        float wAv[8] = {wr0[0], wr0[1], wr0[2], wr0[3], wr1[0], wr1[1], wr1[2], wr1[3]};
        union { short8v s; unsigned q[4]; } pk;
        #pragma unroll
        for (int w = 0; w < 4; ++w) {
          float fa = __uint_as_float(uw[w] << 16);          // channel 2w
          float fb = __uint_as_float(uw[w] & 0xffff0000u);  // channel 2w+1
          float pa = fsilu(fmaf(radial, wAv[2 * w],     hAv[2 * w])     + fa);
          float pb = fsilu(fmaf(radial, wAv[2 * w + 1], hAv[2 * w + 1]) + fb);
          pk.q[w] = cvtpk(pa, pb);
        }
        tf[kt] = pk.s;
      }

      // ---- GEMM1 (swapped): D1^T = ew2 * T^T ; C-init = eb2 (from LDS) ----
      floatx4 acc[4];
      #pragma unroll
      for (int nt = 0; nt < 4; ++nt) acc[nt] = *(const floatx4*)(cvp + nt * 16);
      #pragma unroll
      for (int kt = 0; kt < 2; ++kt)
        #pragma unroll
        for (int nt = 0; nt < 4; ++nt)
          acc[nt] = __builtin_amdgcn_mfma_f32_16x16x32_bf16(bw2[kt][nt], tf[kt], acc[nt], 0, 0, 0);

      // ---- epilogue 1: silu, att (row-dot over n) ----
      float p = 0.f;
      #pragma unroll
      for (int nt = 0; nt < 4; ++nt) {
        floatx4 awv = *(const floatx4*)(cvp + 64 + nt * 16);
        #pragma unroll
        for (int r = 0; r < 4; ++r) {
          float s = fsilu(acc[nt][r]);
          acc[nt][r] = s;
          p = fmaf(s, awv[r], p);
        }
      }
      p += __shfl_xor(p, 16); p += __shfl_xor(p, 32);
      const float att = fsig(p + ab0);

      // ---- e = s*att, agg accum, bf16-pack, bpermute to E^T frags (fused per kt2) ----
      union { short8v s; int u[4]; } ef[2];
      #pragma unroll
      for (int kt2 = 0; kt2 < 2; ++kt2) {
        unsigned PqA[2], PqB[2];
        {
          int nt = kt2 * 2;
          float e0 = acc[nt][0] * att, e1 = acc[nt][1] * att;
          float e2 = acc[nt][2] * att, e3 = acc[nt][3] * att;
          agg4[nt][0] += e0; agg4[nt][1] += e1;
          agg4[nt][2] += e2; agg4[nt][3] += e3;
          PqA[0] = cvtpk(e0, e1); PqA[1] = cvtpk(e2, e3);
          nt = kt2 * 2 + 1;
          e0 = acc[nt][0] * att; e1 = acc[nt][1] * att;
          e2 = acc[nt][2] * att; e3 = acc[nt][3] * att;
          agg4[nt][0] += e0; agg4[nt][1] += e1;
          agg4[nt][2] += e2; agg4[nt][3] += e3;
          PqB[0] = cvtpk(e0, e1); PqB[1] = cvtpk(e2, e3);
        }
        #pragma unroll
        for (int w = 0; w < 4; ++w) {
          int sel = (w < 2) ? selA : selB;
          int v0 = __builtin_amdgcn_ds_bpermute(sel, (int)PqA[w & 1]);
          int v1 = __builtin_amdgcn_ds_bpermute(sel, (int)PqB[w & 1]);
          ef[kt2].u[w] = ghi ? v1 : v0;
        }
      }

      // ---- GEMM2 (swapped): D2^T = chw * E^T ; C-init = chb (from LDS) ----
      #pragma unroll
      for (int nt = 0; nt < 4; ++nt) acc[nt] = *(const floatx4*)(cvp + 128 + nt * 16);
      #pragma unroll
      for (int kt2 = 0; kt2 < 2; ++kt2)
        #pragma unroll
        for (int nt = 0; nt < 4; ++nt)
          acc[nt] = __builtin_amdgcn_mfma_f32_16x16x32_bf16(bwc[kt2][nt], ef[kt2].s, acc[nt], 0, 0, 0);

      // ---- epilogue 2: silu, cww-dot, tanh, delta ----
      float q = 0.f;
      #pragma unroll
      for (int nt = 0; nt < 4; ++nt) {
        floatx4 cwv = *(const floatx4*)(cvp + 192 + nt * 16);
        #pragma unroll
        for (int r = 0; r < 4; ++r)
          q = fmaf(fsilu(acc[nt][r]), cwv[r], q);
      }
      q += __shfl_xor(q, 16); q += __shfl_xor(q, 32);
      const float wvv = ftanh10(q);
      if (g == 0) {
        dp0 = fmaf(dx0, wvv, dp0);
        dp1 = fmaf(dx1, wvv, dp1);
        dp2 = fmaf(dx2, wvv, dp2);
      }
    }

    // ---- final reductions: reduce over edge rows (lr) within wave ----
    #pragma unroll
    for (int nt = 0; nt < 4; ++nt)
      #pragma unroll
      for (int r = 0; r < 4; ++r) {
        float v = agg4[nt][r];
        v += __shfl_xor(v, 1); v += __shfl_xor(v, 2);
        v += __shfl_xor(v, 4); v += __shfl_xor(v, 8);
        agg4[nt][r] = v;
      }
    if (lr == 0) {
      #pragma unroll
      for (int nt = 0; nt < 4; ++nt)
        *(floatx4*)&redagg[wave][nt * 16 + (g << 2)] = agg4[nt];
    }
    dp0 += __shfl_xor(dp0, 1); dp0 += __shfl_xor(dp0, 2); dp0 += __shfl_xor(dp0, 4); dp0 += __shfl_xor(dp0, 8);
    dp1 += __shfl_xor(dp1, 1); dp1 += __shfl_xor(dp1, 2); dp1 += __shfl_xor(dp1, 4); dp1 += __shfl_xor(dp1, 8);
    dp2 += __shfl_xor(dp2, 1); dp2 += __shfl_xor(dp2, 2); dp2 += __shfl_xor(dp2, 4); dp2 += __shfl_xor(dp2, 8);
    if (lane == 0) { sdel[wave][0] = dp0; sdel[wave][1] = dp1; sdel[wave][2] = dp2; }
    __syncthreads();
    if (tid < 64)
      agg_parts[half * 65536 + i0 * 64 + tid] =
          redagg[0][tid] + redagg[1][tid] + redagg[2][tid] + redagg[3][tid];
    else if (tid < 67) {
      int d = tid - 64;
      delta_parts[half * 3072 + i0 * 3 + d] =
          sdel[0][d] + sdel[1][d] + sdel[2][d] + sdel[3][d];
    }
}

// Fused node update + x_new. 256 blocks x 256 thr; block owns 4 nodes.
__global__ __launch_bounds__(256) void node_fused_kernel(
    const float* __restrict__ h, const float* __restrict__ agg0,
    const float* __restrict__ agg1, const float* __restrict__ nw1,
    const float* __restrict__ nb1, const float* __restrict__ nw2,
    const float* __restrict__ nb2, const float* __restrict__ x,
    const float* __restrict__ delta0, const float* __restrict__ delta1,
    const float* __restrict__ Lp, float* __restrict__ outh,
    float* __restrict__ outx)
{
    __shared__ float sps[256];
    const int b = blockIdx.x, tid = threadIdx.x;
    const int gt = b * 256 + tid;
    const int i = gt >> 6, o = gt & 63;
    const float* hrow = h + i * 64;
    const float* w1a = nw1 + o * 128;
    const float* a0 = agg0 + i * 64;
    const float* a1 = agg1 + i * 64;
    const float* w1b = nw1 + o * 128 + 64;
    float acc = nb1[o];
    #pragma unroll
    for (int k = 0; k < 64; ++k) acc = fmaf(hrow[k], w1a[k], acc);
    #pragma unroll
    for (int k = 0; k < 64; ++k) acc = fmaf(a0[k] + a1[k], w1b[k], acc);
    sps[tid] = fsilu(acc);
    __syncthreads();
    const float* srow = sps + (tid & ~63);
    const float* w2row = nw2 + o * 64;
    float acc2 = h[gt] + nb2[o];
    #pragma unroll
    for (int k = 0; k < 64; ++k) acc2 = fmaf(srow[k], w2row[k], acc2);
    outh[gt] = acc2;
    if (tid < 12) {
        int ii = b * 4 + tid / 3, d = tid % 3;
        float L = Lp[0];
        float v = x[ii * 3 + d] + delta0[ii * 3 + d] + delta1[ii * 3 + d];
        outx[ii * 3 + d] = v - L * floorf(v * frcp(L));
    }
}

extern "C" void kernel_launch(void* const* d_in, const int* in_sizes, int n_in,
                              void* d_out, int out_size, void* d_ws, size_t ws_size,
                              hipStream_t stream) {
    const float* h   = (const float*)d_in[0];
    const float* x   = (const float*)d_in[1];
    const float* Lp  = (const float*)d_in[2];
    const float* ew1 = (const float*)d_in[3];
    const float* eb1 = (const float*)d_in[4];
    const float* ew2 = (const float*)d_in[5];
    const float* eb2 = (const float*)d_in[6];
    const float* nw1 = (const float*)d_in[7];
    const float* nb1 = (const float*)d_in[8];
    const float* nw2 = (const float*)d_in[9];
    const float* nb2 = (const float*)d_in[10];
    const float* chw = (const float*)d_in[11];
    const float* chb = (const float*)d_in[12];
    const float* cww = (const float*)d_in[13];
    const float* aw  = (const float*)d_in[14];
    const float* ab  = (const float*)d_in[15];

    float* ws = (float*)d_ws;
    float*          ha     = ws;                            // 65536 f32
    unsigned short* hbb    = (unsigned short*)(ws + 65536); // 65536 u16
    float*          agg0   = ws + 98304;                    // 65536
    float*          agg1   = ws + 163840;                   // 65536
    float*          delta0 = ws + 229376;                   // 3072
    float*          delta1 = ws + 232448;                   // 3072

    float* outh = (float*)d_out;     // 65536
    float* outx = outh + 65536;      // 3072

    precompute_kernel<<<512, 256, 0, stream>>>(h, ew1, eb1, ha, hbb);
    edge_mfma_kernel<<<2048, 256, 0, stream>>>(x, Lp, ha, hbb, ew1, ew2, eb2, chw, chb,
                                               aw, ab, cww, agg0, delta0);
    node_fused_kernel<<<256, 256, 0, stream>>>(h, agg0, agg1, nw1, nb1, nw2, nb2, x,
                                               delta0, delta1, Lp, outh, outx);
}

// Round 18
// 89.911 us; speedup vs baseline: 1.2560x; 1.2560x over previous
//
#include <hip/hip_runtime.h>

#define Nn 1024

typedef __attribute__((ext_vector_type(8))) short short8v;
typedef __attribute__((ext_vector_type(4))) float floatx4;

// hardware-rate reciprocal / sqrt (v_rcp_f32 / v_sqrt_f32, ~1ulp).
__device__ __forceinline__ float frcp(float v)  { return __builtin_amdgcn_rcpf(v); }
__device__ __forceinline__ float fsilu(float v) { return v * frcp(1.0f + __expf(-v)); }
__device__ __forceinline__ float fsig(float v)  { return frcp(1.0f + __expf(-v)); }
__device__ __forceinline__ float ftanh10(float v){ return 10.0f - 20.0f * frcp(__expf(2.0f * v) + 1.0f); }

// 2x f32 -> packed bf16 (RNE) in ONE instruction (no builtin on gfx950 — T12)
__device__ __forceinline__ unsigned cvtpk(float lo, float hi) {
    unsigned r;
    asm("v_cvt_pk_bf16_f32 %0, %1, %2" : "=v"(r) : "v"(lo), "v"(hi));
    return r;
}

union I4S8 { int4 i; short8v s; };

// Kernel A: ha = h@Wa^T + eb1 (f32) ; hbb = bf16(h@Wb^T)
__global__ __launch_bounds__(256) void precompute_kernel(
    const float* __restrict__ h, const float* __restrict__ ew1,
    const float* __restrict__ eb1, float* __restrict__ ha,
    unsigned short* __restrict__ hbb)
{
    int t = blockIdx.x * 256 + threadIdx.x;   // 0 .. 2*65536-1
    int which = t >> 16;
    int rem = t & 65535;
    int i = rem >> 6, o = rem & 63;
    const float* hrow = h + i * 64;
    const float* wrow;
    float acc;
    if (which == 0) { wrow = ew1 + o * 130;      acc = eb1[o]; }
    else            { wrow = ew1 + o * 130 + 64; acc = 0.0f;   }
    #pragma unroll
    for (int k = 0; k < 64; ++k) acc = fmaf(hrow[k], wrow[k], acc);
    if (which == 0) ha[rem]  = acc;
    else            hbb[rem] = (unsigned short)(cvtpk(acc, acc) & 0xffffu);
}

// Edge pipeline. 2048 blocks x 256 thr (4 waves): block b owns node b>>1 and
// j-half b&1; wave owns 128 j's in 8 chunks of 16. R14 body (best, 90.4us)
// + att-DEFERRAL: att is scalar per edge, so (att*S)@chw^T = att*(S@chw^T).
// Pack/bpermute S immediately after the epilogue-1 silu — the att reduction
// (2 serial shfls + sigmoid) no longer gates GEMM2's operand assembly; att
// folds in post-GEMM via fmaf(att, acc2, chb). Removes ~100+ cyc from the
// per-chunk critical path; numerically equivalent (att applied in f32).
__global__ __launch_bounds__(256) __attribute__((amdgpu_waves_per_eu(4, 8)))
void edge_mfma_kernel(
    const float* __restrict__ x, const float* __restrict__ Lp,
    const float* __restrict__ ha, const unsigned short* __restrict__ hbb,
    const float* __restrict__ ew1, const float* __restrict__ ew2,
    const float* __restrict__ eb2, const float* __restrict__ chw,
    const float* __restrict__ chb, const float* __restrict__ aw,
    const float* __restrict__ ab, const float* __restrict__ cww,
    float* __restrict__ agg_parts, float* __restrict__ delta_parts)
{
    __shared__ __align__(16) int4 Wlds[1024];     // [w2|wc][kt][nt][lane] packed bf16 frags, 16KB
    __shared__ __align__(16) float cvec[384];     // eb2|aw|chb|cww|ha_row|wr_row (64 each)
    __shared__ float redagg[4][64];
    __shared__ float sdel[4][3];

    const int tid  = threadIdx.x;
    const int wave = tid >> 6, lane = tid & 63;
    const int lr = lane & 15, g = lane >> 4;
    const int i0 = blockIdx.x >> 1;
    const int half = blockIdx.x & 1;
    const int jbase = half * 512 + wave * 128;
    const int ghi  = g >> 1;
    const int selA = (lr + ((g & 1) << 5)) << 2;   // bpermute byte addr
    const int selB = selA + 64;
    const int4* WldsF = &Wlds[0];

    // wave 0 stages packed weight fragments into LDS: row n = lane&15, k 8-contig per g.
    if (wave == 0) {
      #pragma unroll
      for (int kt = 0; kt < 2; ++kt)
        #pragma unroll
        for (int nt = 0; nt < 4; ++nt) {
          int n = nt * 16 + lr;
          int k0 = kt * 32 + g * 8;
          float4 lo = *(const float4*)(ew2 + n * 64 + k0);
          float4 hi = *(const float4*)(ew2 + n * 64 + k0 + 4);
          Wlds[(kt * 4 + nt) * 64 + lane] = make_int4(
              (int)cvtpk(lo.x, lo.y), (int)cvtpk(lo.z, lo.w),
              (int)cvtpk(hi.x, hi.y), (int)cvtpk(hi.z, hi.w));
          lo = *(const float4*)(chw + n * 64 + k0);
          hi = *(const float4*)(chw + n * 64 + k0 + 4);
          Wlds[512 + (kt * 4 + nt) * 64 + lane] = make_int4(
              (int)cvtpk(lo.x, lo.y), (int)cvtpk(lo.z, lo.w),
              (int)cvtpk(hi.x, hi.y), (int)cvtpk(hi.z, hi.w));
        }
    }
    // constant vectors -> LDS (re-read per chunk; keeps them out of registers)
    if (tid < 64) {
      cvec[tid]       = eb2[tid];
      cvec[64 + tid]  = aw[tid];
      cvec[128 + tid] = chb[tid];
      cvec[192 + tid] = cww[tid];
      cvec[256 + tid] = ha[i0 * 64 + tid];
      cvec[320 + tid] = ew1[tid * 130 + 128] + ew1[tid * 130 + 129];
    }

    const float L = Lp[0], invL = frcp(L);
    const float ab0 = ab[0];

    floatx4 agg4[4];
    #pragma unroll
    for (int nt = 0; nt < 4; ++nt) agg4[nt] = (floatx4){0.f, 0.f, 0.f, 0.f};
    float dp0 = 0.f, dp1 = 0.f, dp2 = 0.f;

    __syncthreads();

    const float xi0 = x[i0 * 3 + 0], xi1 = x[i0 * 3 + 1], xi2 = x[i0 * 3 + 2];

    // prefetch bf16 hb fragment rows for chunk 0 (this lane's edge row lr)
    int4 hpre0, hpre1;
    {
      const unsigned short* hn = hbb + (jbase + lr) * 64 + g * 8;
      hpre0 = *(const int4*)(hn);        // channels kt=0: g*8 .. +7
      hpre1 = *(const int4*)(hn + 32);   // channels kt=1: 32+g*8 .. +7
    }

    for (int jc = 0; jc < 8; ++jc) {
      // laundered indices: keep per-chunk LDS reads opaque to LICM
      unsigned lidx = (unsigned)lane;
      asm volatile("" : "+v"(lidx));
      unsigned cb = (unsigned)(g << 4);          // g*4 floats (bias vectors)
      asm volatile("" : "+v"(cb));
      unsigned hbo = (unsigned)(g << 5);         // g*8 floats (ha/wr rows)
      asm volatile("" : "+v"(hbo));
      const float* cvp = (const float*)((const char*)cvec + cb);
      const float* hvp = (const float*)((const char*)cvec + 1024 + hbo);

      int4 hc0 = hpre0, hc1 = hpre1;
      if (jc < 7) {   // issue next chunk's hb loads NOW; latency hides under compute
        const unsigned short* hn = hbb + (jbase + (jc + 1) * 16 + lr) * 64 + g * 8;
        hpre0 = *(const int4*)(hn);
        hpre1 = *(const int4*)(hn + 32);
      }

      // ---- geometry for own edge (i0, j): all lanes, row = lr (x is L1-hot) ----
      const int j = jbase + jc * 16 + lr;
      float xd0 = xi0 - x[j * 3 + 0];
      float xd1 = xi1 - x[j * 3 + 1];
      float xd2 = xi2 - x[j * 3 + 2];
      float d0 = xd0 - L * floorf(fmaf(xd0, invL, 0.5f));
      float d1 = xd1 - L * floorf(fmaf(xd1, invL, 0.5f));
      float d2 = xd2 - L * floorf(fmaf(xd2, invL, 0.5f));
      float radial = d0 * d0 + d1 * d1 + d2 * d2;
      float cinv = frcp(__builtin_amdgcn_sqrtf(radial + 1e-8f) + 1.0f);
      float dx0 = d0 * cinv, dx1 = d1 * cinv, dx2 = d2 * cinv;

      // ---- build T fragment in registers: silu(ha + hb + radial*wr) -> bf16 ----
      short8v tf[2];
      #pragma unroll
      for (int kt = 0; kt < 2; ++kt) {
        const int4 u = kt ? hc1 : hc0;
        unsigned uw[4] = {(unsigned)u.x, (unsigned)u.y, (unsigned)u.z, (unsigned)u.w};
        floatx4 ha0 = *(const floatx4*)(hvp + kt * 32);
        floatx4 ha1 = *(const floatx4*)(hvp + kt * 32 + 4);
        floatx4 wr0 = *(const floatx4*)(hvp + 64 + kt * 32);
        floatx4 wr1 = *(const floatx4*)(hvp + 64 + kt * 32 + 4);
        float hAv[8] = {ha0[0], ha0[1], ha0[2], ha0[3], ha1[0], ha1[1], ha1[2], ha1[3]};
        float wAv[8] = {wr0[0], wr0[1], wr0[2], wr0[3], wr1[0], wr1[1], wr1[2], wr1[3]};
        union { short8v s; unsigned q[4]; } pk;
        #pragma unroll
        for (int w = 0; w < 4; ++w) {
          float fa = __uint_as_float(uw[w] << 16);          // channel 2w
          float fb = __uint_as_float(uw[w] & 0xffff0000u);  // channel 2w+1
          float pa = fsilu(fmaf(radial, wAv[2 * w],     hAv[2 * w])     + fa);
          float pb = fsilu(fmaf(radial, wAv[2 * w + 1], hAv[2 * w + 1]) + fb);
          pk.q[w] = cvtpk(pa, pb);
        }
        tf[kt] = pk.s;
      }

      // ---- GEMM1 (swapped): D1^T = ew2 * T^T ; C-init = eb2 (from LDS) ----
      floatx4 acc[4];
      #pragma unroll
      for (int nt = 0; nt < 4; ++nt) acc[nt] = *(const floatx4*)(cvp + nt * 16);
      #pragma unroll
      for (int kt = 0; kt < 2; ++kt)
        #pragma unroll
        for (int nt = 0; nt < 4; ++nt) {
          I4S8 wv; wv.i = WldsF[(kt * 4 + nt) * 64 + lidx];
          acc[nt] = __builtin_amdgcn_mfma_f32_16x16x32_bf16(wv.s, tf[kt], acc[nt], 0, 0, 0);
        }

      // ---- epilogue 1: silu -> s (stored in acc); p-dot alongside ----
      float p = 0.f;
      #pragma unroll
      for (int nt = 0; nt < 4; ++nt) {
        floatx4 awv = *(const floatx4*)(cvp + 64 + nt * 16);
        #pragma unroll
        for (int r = 0; r < 4; ++r) {
          float s = fsilu(acc[nt][r]);
          acc[nt][r] = s;
          p = fmaf(s, awv[r], p);
        }
      }

      // ---- pack S (pre-att!) and bpermute to E^T frags — no att dependence ----
      union { short8v s; int u[4]; } ef[2];
      #pragma unroll
      for (int kt2 = 0; kt2 < 2; ++kt2) {
        unsigned PqA[2], PqB[2];
        PqA[0] = cvtpk(acc[kt2 * 2][0],     acc[kt2 * 2][1]);
        PqA[1] = cvtpk(acc[kt2 * 2][2],     acc[kt2 * 2][3]);
        PqB[0] = cvtpk(acc[kt2 * 2 + 1][0], acc[kt2 * 2 + 1][1]);
        PqB[1] = cvtpk(acc[kt2 * 2 + 1][2], acc[kt2 * 2 + 1][3]);
        #pragma unroll
        for (int w = 0; w < 4; ++w) {
          int sel = (w < 2) ? selA : selB;
          int v0 = __builtin_amdgcn_ds_bpermute(sel, (int)PqA[w & 1]);
          int v1 = __builtin_amdgcn_ds_bpermute(sel, (int)PqB[w & 1]);
          ef[kt2].u[w] = ghi ? v1 : v0;
        }
      }

      // ---- att reduction (overlaps bpermute/GEMM2 in the scheduler) ----
      p += __shfl_xor(p, 16); p += __shfl_xor(p, 32);
      const float att = fsig(p + ab0);

      // ---- agg += att * s (16 FMA; off the GEMM2 path) ----
      #pragma unroll
      for (int nt = 0; nt < 4; ++nt)
        #pragma unroll
        for (int r = 0; r < 4; ++r)
          agg4[nt][r] = fmaf(att, acc[nt][r], agg4[nt][r]);

      // ---- GEMM2 (swapped): D2s^T = chw * S^T ; zero-init, att folded after ----
      floatx4 acc2[4];
      #pragma unroll
      for (int nt = 0; nt < 4; ++nt) acc2[nt] = (floatx4){0.f, 0.f, 0.f, 0.f};
      #pragma unroll
      for (int kt2 = 0; kt2 < 2; ++kt2)
        #pragma unroll
        for (int nt = 0; nt < 4; ++nt) {
          I4S8 wv; wv.i = WldsF[512 + (kt2 * 4 + nt) * 64 + lidx];
          acc2[nt] = __builtin_amdgcn_mfma_f32_16x16x32_bf16(wv.s, ef[kt2].s, acc2[nt], 0, 0, 0);
        }

      // ---- epilogue 2: silu(att*D2s + chb), cww-dot, tanh, delta ----
      float q = 0.f;
      #pragma unroll
      for (int nt = 0; nt < 4; ++nt) {
        floatx4 chbv = *(const floatx4*)(cvp + 128 + nt * 16);
        floatx4 cwv  = *(const floatx4*)(cvp + 192 + nt * 16);
        #pragma unroll
        for (int r = 0; r < 4; ++r) {
          float c = fsilu(fmaf(att, acc2[nt][r], chbv[r]));
          q = fmaf(c, cwv[r], q);
        }
      }
      q += __shfl_xor(q, 16); q += __shfl_xor(q, 32);
      const float wvv = ftanh10(q);
      if (g == 0) {
        dp0 = fmaf(dx0, wvv, dp0);
        dp1 = fmaf(dx1, wvv, dp1);
        dp2 = fmaf(dx2, wvv, dp2);
      }
    }

    // ---- final reductions: reduce over edge rows (lr) within wave ----
    #pragma unroll
    for (int nt = 0; nt < 4; ++nt)
      #pragma unroll
      for (int r = 0; r < 4; ++r) {
        float v = agg4[nt][r];
        v += __shfl_xor(v, 1); v += __shfl_xor(v, 2);
        v += __shfl_xor(v, 4); v += __shfl_xor(v, 8);
        agg4[nt][r] = v;
      }
    if (lr == 0) {
      #pragma unroll
      for (int nt = 0; nt < 4; ++nt)
        *(floatx4*)&redagg[wave][nt * 16 + (g << 2)] = agg4[nt];
    }
    dp0 += __shfl_xor(dp0, 1); dp0 += __shfl_xor(dp0, 2); dp0 += __shfl_xor(dp0, 4); dp0 += __shfl_xor(dp0, 8);
    dp1 += __shfl_xor(dp1, 1); dp1 += __shfl_xor(dp1, 2); dp1 += __shfl_xor(dp1, 4); dp1 += __shfl_xor(dp1, 8);
    dp2 += __shfl_xor(dp2, 1); dp2 += __shfl_xor(dp2, 2); dp2 += __shfl_xor(dp2, 4); dp2 += __shfl_xor(dp2, 8);
    if (lane == 0) { sdel[wave][0] = dp0; sdel[wave][1] = dp1; sdel[wave][2] = dp2; }
    __syncthreads();
    if (tid < 64)
      agg_parts[half * 65536 + i0 * 64 + tid] =
          redagg[0][tid] + redagg[1][tid] + redagg[2][tid] + redagg[3][tid];
    else if (tid < 67) {
      int d = tid - 64;
      delta_parts[half * 3072 + i0 * 3 + d] =
          sdel[0][d] + sdel[1][d] + sdel[2][d] + sdel[3][d];
    }
}

// Fused node update + x_new. 256 blocks x 256 thr; block owns 4 nodes.
__global__ __launch_bounds__(256) void node_fused_kernel(
    const float* __restrict__ h, const float* __restrict__ agg0,
    const float* __restrict__ agg1, const float* __restrict__ nw1,
    const float* __restrict__ nb1, const float* __restrict__ nw2,
    const float* __restrict__ nb2, const float* __restrict__ x,
    const float* __restrict__ delta0, const float* __restrict__ delta1,
    const float* __restrict__ Lp, float* __restrict__ outh,
    float* __restrict__ outx)
{
    __shared__ float sps[256];
    const int b = blockIdx.x, tid = threadIdx.x;
    const int gt = b * 256 + tid;
    const int i = gt >> 6, o = gt & 63;
    const float* hrow = h + i * 64;
    const float* w1a = nw1 + o * 128;
    const float* a0 = agg0 + i * 64;
    const float* a1 = agg1 + i * 64;
    const float* w1b = nw1 + o * 128 + 64;
    float acc = nb1[o];
    #pragma unroll
    for (int k = 0; k < 64; ++k) acc = fmaf(hrow[k], w1a[k], acc);
    #pragma unroll
    for (int k = 0; k < 64; ++k) acc = fmaf(a0[k] + a1[k], w1b[k], acc);
    sps[tid] = fsilu(acc);
    __syncthreads();
    const float* srow = sps + (tid & ~63);
    const float* w2row = nw2 + o * 64;
    float acc2 = h[gt] + nb2[o];
    #pragma unroll
    for (int k = 0; k < 64; ++k) acc2 = fmaf(srow[k], w2row[k], acc2);
    outh[gt] = acc2;
    if (tid < 12) {
        int ii = b * 4 + tid / 3, d = tid % 3;
        float L = Lp[0];
        float v = x[ii * 3 + d] + delta0[ii * 3 + d] + delta1[ii * 3 + d];
        outx[ii * 3 + d] = v - L * floorf(v * frcp(L));
    }
}

extern "C" void kernel_launch(void* const* d_in, const int* in_sizes, int n_in,
                              void* d_out, int out_size, void* d_ws, size_t ws_size,
                              hipStream_t stream) {
    const float* h   = (const float*)d_in[0];
    const float* x   = (const float*)d_in[1];
    const float* Lp  = (const float*)d_in[2];
    const float* ew1 = (const float*)d_in[3];
    const float* eb1 = (const float*)d_in[4];
    const float* ew2 = (const float*)d_in[5];
    const float* eb2 = (const float*)d_in[6];
    const float* nw1 = (const float*)d_in[7];
    const float* nb1 = (const float*)d_in[8];
    const float* nw2 = (const float*)d_in[9];
    const float* nb2 = (const float*)d_in[10];
    const float* chw = (const float*)d_in[11];
    const float* chb = (const float*)d_in[12];
    const float* cww = (const float*)d_in[13];
    const float* aw  = (const float*)d_in[14];
    const float* ab  = (const float*)d_in[15];

    float* ws = (float*)d_ws;
    float*          ha     = ws;                            // 65536 f32
    unsigned short* hbb    = (unsigned short*)(ws + 65536); // 65536 u16
    float*          agg0   = ws + 98304;                    // 65536
    float*          agg1   = ws + 163840;                   // 65536
    float*          delta0 = ws + 229376;                   // 3072
    float*          delta1 = ws + 232448;                   // 3072

    float* outh = (float*)d_out;     // 65536
    float* outx = outh + 65536;      // 3072

    precompute_kernel<<<512, 256, 0, stream>>>(h, ew1, eb1, ha, hbb);
    edge_mfma_kernel<<<2048, 256, 0, stream>>>(x, Lp, ha, hbb, ew1, ew2, eb2, chw, chb,
                                               aw, ab, cww, agg0, delta0);
    node_fused_kernel<<<256, 256, 0, stream>>>(h, agg0, agg1, nw1, nb1, nw2, nb2, x,
                                               delta0, delta1, Lp, outh, outx);
}